// Round 1
// baseline (201.172 us; speedup 1.0000x reference)
//
#include <hip/hip_runtime.h>
#include <hip/hip_bf16.h>

// ---------------- problem constants ----------------
constexpr int Bq = 16384;   // batch
constexpr int Cc = 256;     // hidden
constexpr int Ss = 40;      // prev/out width
constexpr int KD1 = 320;    // 296 padded to 320 (5 x 64)

// ---------------- ws layout (bytes) ----------------
constexpr size_t O_WD1  = 0;          // bf16 [256][320]  163840
constexpr size_t O_WD2  = 0x30000;    // bf16 [256][256]  131072
constexpr size_t O_WG1  = 0x50000;    // bf16 [1536][256] 786432
constexpr size_t O_WG2  = 0x110000;
constexpr size_t O_WG3  = 0x1D0000;
constexpr size_t O_WOUT = 0x290000;   // bf16 [128][256]  65536
constexpr size_t O_BD1  = 0x2A0000;   // f32 [256]
constexpr size_t O_BD2  = 0x2A0400;
constexpr size_t O_BG1  = 0x2A0800;   // f32 [1536]
constexpr size_t O_BG2  = 0x2A2000;
constexpr size_t O_BG3  = 0x2A3800;
constexpr size_t O_BOUT = 0x2A5000;   // f32 [128]
constexpr size_t O_ACTA = 0x2B0000;   // bf16 [B][256]  8 MB
constexpr size_t O_ACTB = 0xAB0000;   // bf16 [B][256]
constexpr size_t O_H1   = 0x12B0000;  // bf16 [B][256]
constexpr size_t O_H2   = 0x1AB0000;
constexpr size_t O_H3   = 0x22B0000;
constexpr size_t O_XD1  = 0x2AB0000;  // bf16 [B][320] 10.5 MB  (union with GATES)
constexpr size_t O_GATES= 0x2AB0000;  // bf16 [rch][1536] up to 50.3 MB

// d_out element offsets (fp32): out[B,40], g1[B,256], g2, g3
constexpr size_t GO_OUT = 0;
constexpr size_t GO_G1  = (size_t)Bq * Ss;              // 655360
constexpr size_t GO_G2  = GO_G1 + (size_t)Bq * Cc;      // 4849664
constexpr size_t GO_G3  = GO_G2 + (size_t)Bq * Cc;      // 9043968

typedef __attribute__((ext_vector_type(8))) short bf16x8;
typedef __attribute__((ext_vector_type(4))) float f32x4;

__device__ __forceinline__ float bf2f(unsigned short h) {
    union { unsigned u; float f; } v; v.u = ((unsigned)h) << 16; return v.f;
}
__device__ __forceinline__ unsigned short f2bf(float f) {
    union { float f; unsigned u; } v; v.f = f;
    unsigned u = v.u;
    return (unsigned short)((u + 0x7FFFu + ((u >> 16) & 1u)) >> 16);
}
__device__ __forceinline__ float sigf(float x) { return 1.f / (1.f + __expf(-x)); }

// ---------------- prep: pack weights/biases, convert activations ----------------
constexpr long NW1 = 256L * 320;        // Wd1 padded
constexpr long NW2 = 256L * 256;        // Wd2
constexpr long NWG = 1536L * 256;       // per-GRU gate weights (x3)
constexpr long NWO = 128L * 256;        // Wout padded rows
constexpr long NB  = 256 + 256 + 1536L * 3 + 128;
constexpr long NX  = (long)Bq * KD1;    // Xd1
constexpr long NH  = (long)Bq * Cc;     // per h (x3)
constexpr long NPREP = NW1 + NW2 + 3 * NWG + NWO + NB + NX + 3 * NH;

__global__ void prep_kernel(
    const float* __restrict__ cond, const float* __restrict__ prev,
    const float* __restrict__ h1, const float* __restrict__ h2, const float* __restrict__ h3,
    const float* __restrict__ w_d1, const float* __restrict__ b_d1,
    const float* __restrict__ w_d2, const float* __restrict__ b_d2,
    const float* __restrict__ w_ih1, const float* __restrict__ w_hh1,
    const float* __restrict__ b_ih1, const float* __restrict__ b_hh1,
    const float* __restrict__ w_ih2, const float* __restrict__ w_hh2,
    const float* __restrict__ b_ih2, const float* __restrict__ b_hh2,
    const float* __restrict__ w_ih3, const float* __restrict__ w_hh3,
    const float* __restrict__ b_ih3, const float* __restrict__ b_hh3,
    const float* __restrict__ w_out, const float* __restrict__ b_out,
    char* __restrict__ ws)
{
    long e = (long)blockIdx.x * blockDim.x + threadIdx.x;
    if (e >= NPREP) return;

    if (e < NW1) {  // Wd1 [256][320], src [256][296]
        int n = (int)(e / KD1), k = (int)(e % KD1);
        float v = (k < 296) ? w_d1[(long)n * 296 + k] : 0.f;
        ((unsigned short*)(ws + O_WD1))[e] = f2bf(v);
        return;
    }
    e -= NW1;
    if (e < NW2) {
        ((unsigned short*)(ws + O_WD2))[e] = f2bf(w_d2[e]);
        return;
    }
    e -= NW2;
    if (e < 3 * NWG) {  // [w_ih; w_hh] -> [1536][256]
        int g = (int)(e / NWG); long r = e % NWG;
        int n = (int)(r / 256), k = (int)(r % 256);
        const float* wih = (g == 0) ? w_ih1 : (g == 1) ? w_ih2 : w_ih3;
        const float* whh = (g == 0) ? w_hh1 : (g == 1) ? w_hh2 : w_hh3;
        size_t off = (g == 0) ? O_WG1 : (g == 1) ? O_WG2 : O_WG3;
        float v = (n < 768) ? wih[(long)n * 256 + k] : whh[(long)(n - 768) * 256 + k];
        ((unsigned short*)(ws + off))[r] = f2bf(v);
        return;
    }
    e -= 3 * NWG;
    if (e < NWO) {  // Wout [128][256], rows >= 40 zero
        int n = (int)(e / 256), k = (int)(e % 256);
        float v = (n < Ss) ? w_out[(long)n * 256 + k] : 0.f;
        ((unsigned short*)(ws + O_WOUT))[e] = f2bf(v);
        return;
    }
    e -= NWO;
    if (e < NB) {  // biases, fp32 copies
        long j = e;
        if (j < 256) { ((float*)(ws + O_BD1))[j] = b_d1[j]; return; } j -= 256;
        if (j < 256) { ((float*)(ws + O_BD2))[j] = b_d2[j]; return; } j -= 256;
        if (j < 1536) { ((float*)(ws + O_BG1))[j] = (j < 768) ? b_ih1[j] : b_hh1[j - 768]; return; } j -= 1536;
        if (j < 1536) { ((float*)(ws + O_BG2))[j] = (j < 768) ? b_ih2[j] : b_hh2[j - 768]; return; } j -= 1536;
        if (j < 1536) { ((float*)(ws + O_BG3))[j] = (j < 768) ? b_ih3[j] : b_hh3[j - 768]; return; } j -= 1536;
        ((float*)(ws + O_BOUT))[j] = (j < Ss) ? b_out[j] : 0.f;
        return;
    }
    e -= NB;
    if (e < NX) {  // Xd1 [B][320] = [cond | prev | 0]
        int b = (int)(e / KD1), k = (int)(e % KD1);
        float v;
        if (k < 256) v = cond[(long)b * 256 + k];
        else if (k < 296) v = prev[(long)b * Ss + (k - 256)];
        else v = 0.f;
        ((unsigned short*)(ws + O_XD1))[e] = f2bf(v);
        return;
    }
    e -= NX;
    {   // h1..h3 bf16
        int g = (int)(e / NH); long r = e % NH;
        const float* hp = (g == 0) ? h1 : (g == 1) ? h2 : h3;
        size_t off = (g == 0) ? O_H1 : (g == 1) ? O_H2 : O_H3;
        ((unsigned short*)(ws + off))[r] = f2bf(hp[r]);
    }
}

// ---------------- GEMM: C[r,n] = sum_k A[r,k] * W[n,k] + bias[n] ----------------
// m97 structure: 128x128 tile, BK=64, 4 waves (2x2), 16x16x32 bf16 MFMA,
// global_load_lds width 16, single LDS buffer, 2 barriers per K-step.
// EPI: 0 = tanh -> bf16 (ldo), 1 = raw -> bf16 (ldo), 2 = tanh -> f32, cols < Ss only
constexpr int BM = 128, BN = 128, BK = 64;

template<int EPI>
__launch_bounds__(256, 2)
__global__ void gemm_bt(const unsigned short* __restrict__ A,
                        const unsigned short* __restrict__ Ah,
                        const unsigned short* __restrict__ W,
                        const float* __restrict__ bias,
                        void* __restrict__ outp,
                        int Ka, int nsplit, int ldo)
{
    __shared__ __align__(16) unsigned short sA[BM * BK];
    __shared__ __align__(16) unsigned short sB[BN * BK];

    const int tid  = threadIdx.x;
    const int lane = tid & 63;
    const int wid  = tid >> 6;
    const int wm   = wid >> 1, wn = wid & 1;
    const long brow = (long)blockIdx.x * BM;
    const long bcol = (long)blockIdx.y * BN;
    const unsigned short* Ause = (bcol < nsplit) ? A : Ah;

    f32x4 acc[4][4];
#pragma unroll
    for (int i = 0; i < 4; i++)
#pragma unroll
        for (int j = 0; j < 4; j++) acc[i][j] = (f32x4){0.f, 0.f, 0.f, 0.f};

    const int nkt = Ka / BK;
    for (int kt = 0; kt < nkt; ++kt) {
        const long k0 = (long)kt * BK;
#pragma unroll
        for (int i = 0; i < 4; i++) {
            const int cb = i * 256 + wid * 64;     // wave-uniform chunk base
            const int c  = cb + lane;              // per-lane chunk
            const int row = c >> 3, seg = c & 7;   // 8 chunks (16B) per 64-elem row
            const unsigned short* ga = Ause + (brow + row) * Ka + k0 + seg * 8;
            const unsigned short* gw = W    + (bcol + row) * Ka + k0 + seg * 8;
            __builtin_amdgcn_global_load_lds(
                (const __attribute__((address_space(1))) void*)ga,
                (__attribute__((address_space(3))) void*)(sA + (size_t)cb * 8), 16, 0, 0);
            __builtin_amdgcn_global_load_lds(
                (const __attribute__((address_space(1))) void*)gw,
                (__attribute__((address_space(3))) void*)(sB + (size_t)cb * 8), 16, 0, 0);
        }
        __syncthreads();   // compiler emits vmcnt(0) drain before barrier

#pragma unroll
        for (int kk = 0; kk < 2; ++kk) {
            bf16x8 af[4], bfr[4];
#pragma unroll
            for (int mf = 0; mf < 4; ++mf)
                af[mf] = *(const bf16x8*)&sA[(wm * 64 + mf * 16 + (lane & 15)) * BK + kk * 32 + (lane >> 4) * 8];
#pragma unroll
            for (int nf = 0; nf < 4; ++nf)
                bfr[nf] = *(const bf16x8*)&sB[(wn * 64 + nf * 16 + (lane & 15)) * BK + kk * 32 + (lane >> 4) * 8];
#pragma unroll
            for (int mf = 0; mf < 4; ++mf)
#pragma unroll
                for (int nf = 0; nf < 4; ++nf)
                    acc[mf][nf] = __builtin_amdgcn_mfma_f32_16x16x32_bf16(af[mf], bfr[nf], acc[mf][nf], 0, 0, 0);
        }
        __syncthreads();
    }

    // epilogue: C/D layout col = lane&15, row = (lane>>4)*4 + j
    const int lr4 = (lane >> 4) * 4;
    const int lc  = lane & 15;
#pragma unroll
    for (int mf = 0; mf < 4; ++mf) {
#pragma unroll
        for (int nf = 0; nf < 4; ++nf) {
            const long n = bcol + wn * 64 + nf * 16 + lc;
            const float bs = bias[n];
            f32x4 v = acc[mf][nf];
#pragma unroll
            for (int j = 0; j < 4; ++j) {
                const long r = brow + wm * 64 + mf * 16 + lr4 + j;
                float val = v[j] + bs;
                if constexpr (EPI == 0) {
                    ((unsigned short*)outp)[r * ldo + n] = f2bf(tanhf(val));
                } else if constexpr (EPI == 1) {
                    ((unsigned short*)outp)[r * ldo + n] = f2bf(val);
                } else {
                    if (n < Ss) ((float*)outp)[r * Ss + n] = tanhf(val);
                }
            }
        }
    }
}

// ---------------- GRU elementwise ----------------
// gates: bf16 [rch][1536] local rows: [i_r i_z i_n | h_r h_z h_n] each 256 wide
__global__ void gru_elem(const unsigned short* __restrict__ gates,
                         const float* __restrict__ h,
                         float* __restrict__ gout,        // d_out + region, global rows
                         unsigned short* __restrict__ actout, // bf16 [B][256], global rows
                         int r0, int rch)
{
    int u = blockIdx.x * blockDim.x + threadIdx.x;
    if (u >= rch * 32) return;
    const int lr = u >> 5;
    const int c8 = (u & 31) << 3;
    const long b = (long)r0 + lr;

    const unsigned short* grow = gates + (size_t)lr * 1536 + c8;
    bf16x8 ir  = *(const bf16x8*)(grow);
    bf16x8 iz  = *(const bf16x8*)(grow + 256);
    bf16x8 inn = *(const bf16x8*)(grow + 512);
    bf16x8 hr  = *(const bf16x8*)(grow + 768);
    bf16x8 hz  = *(const bf16x8*)(grow + 1024);
    bf16x8 hn  = *(const bf16x8*)(grow + 1280);

    float hvf[8];
    *(float4*)&hvf[0] = *(const float4*)(h + b * 256 + c8);
    *(float4*)&hvf[4] = *(const float4*)(h + b * 256 + c8 + 4);

    float gf[8];
    unsigned short gb[8];
#pragma unroll
    for (int j = 0; j < 8; ++j) {
        float r = sigf(bf2f((unsigned short)ir[j]) + bf2f((unsigned short)hr[j]));
        float z = sigf(bf2f((unsigned short)iz[j]) + bf2f((unsigned short)hz[j]));
        float n = tanhf(bf2f((unsigned short)inn[j]) + r * bf2f((unsigned short)hn[j]));
        float g = (1.f - z) * n + z * hvf[j];
        gf[j] = g; gb[j] = f2bf(g);
    }
    *(float4*)(gout + b * 256 + c8)     = make_float4(gf[0], gf[1], gf[2], gf[3]);
    *(float4*)(gout + b * 256 + c8 + 4) = make_float4(gf[4], gf[5], gf[6], gf[7]);
    bf16x8 ov;
#pragma unroll
    for (int j = 0; j < 8; ++j) ov[j] = (short)gb[j];
    *(bf16x8*)(actout + b * 256 + c8) = ov;
}

// ---------------- host launch ----------------
extern "C" void kernel_launch(void* const* d_in, const int* in_sizes, int n_in,
                              void* d_out, int out_size, void* d_ws, size_t ws_size,
                              hipStream_t stream)
{
    const float* cond  = (const float*)d_in[0];
    const float* prev  = (const float*)d_in[1];
    const float* h1    = (const float*)d_in[2];
    const float* h2    = (const float*)d_in[3];
    const float* h3    = (const float*)d_in[4];
    const float* w_d1  = (const float*)d_in[5];
    const float* b_d1  = (const float*)d_in[6];
    const float* w_d2  = (const float*)d_in[7];
    const float* b_d2  = (const float*)d_in[8];
    const float* w_ih1 = (const float*)d_in[9];
    const float* w_hh1 = (const float*)d_in[10];
    const float* b_ih1 = (const float*)d_in[11];
    const float* b_hh1 = (const float*)d_in[12];
    const float* w_ih2 = (const float*)d_in[13];
    const float* w_hh2 = (const float*)d_in[14];
    const float* b_ih2 = (const float*)d_in[15];
    const float* b_hh2 = (const float*)d_in[16];
    const float* w_ih3 = (const float*)d_in[17];
    const float* w_hh3 = (const float*)d_in[18];
    const float* b_ih3 = (const float*)d_in[19];
    const float* b_hh3 = (const float*)d_in[20];
    const float* w_out = (const float*)d_in[21];
    const float* b_out = (const float*)d_in[22];

    char* ws = (char*)d_ws;
    float* out_f = (float*)d_out;

    const unsigned short* WD1  = (const unsigned short*)(ws + O_WD1);
    const unsigned short* WD2  = (const unsigned short*)(ws + O_WD2);
    const unsigned short* WOUT = (const unsigned short*)(ws + O_WOUT);
    const float* BD1  = (const float*)(ws + O_BD1);
    const float* BD2  = (const float*)(ws + O_BD2);
    const float* BOUT = (const float*)(ws + O_BOUT);
    const unsigned short* XD1 = (const unsigned short*)(ws + O_XD1);
    unsigned short* ACTA = (unsigned short*)(ws + O_ACTA);
    unsigned short* ACTB = (unsigned short*)(ws + O_ACTB);
    unsigned short* GATES = (unsigned short*)(ws + O_GATES);

    const unsigned short* WG[3] = {
        (const unsigned short*)(ws + O_WG1),
        (const unsigned short*)(ws + O_WG2),
        (const unsigned short*)(ws + O_WG3) };
    const float* BG[3] = {
        (const float*)(ws + O_BG1), (const float*)(ws + O_BG2), (const float*)(ws + O_BG3) };
    const unsigned short* HB[3] = {
        (const unsigned short*)(ws + O_H1),
        (const unsigned short*)(ws + O_H2),
        (const unsigned short*)(ws + O_H3) };
    const float* HF[3] = { h1, h2, h3 };
    const size_t GOFF[3] = { GO_G1, GO_G2, GO_G3 };

    // 1) prep
    {
        long blocks = (NPREP + 255) / 256;
        prep_kernel<<<dim3((unsigned)blocks), dim3(256), 0, stream>>>(
            cond, prev, h1, h2, h3, w_d1, b_d1, w_d2, b_d2,
            w_ih1, w_hh1, b_ih1, b_hh1, w_ih2, w_hh2, b_ih2, b_hh2,
            w_ih3, w_hh3, b_ih3, b_hh3, w_out, b_out, ws);
    }

    // 2) dense1: Xd1[B,320] -> tanh -> ACTA bf16 [B,256]
    gemm_bt<0><<<dim3(Bq / BM, Cc / BN), dim3(256), 0, stream>>>(
        XD1, XD1, WD1, BD1, ACTA, KD1, 1 << 30, Cc);
    // 3) dense2: ACTA -> tanh -> ACTB
    gemm_bt<0><<<dim3(Bq / BM, Cc / BN), dim3(256), 0, stream>>>(
        ACTA, ACTA, WD2, BD2, ACTB, Cc, 1 << 30, Cc);

    // 4) GRUs (gates GEMM + elementwise), chunked over B if ws is small
    int nch = 1;
    while (O_GATES + (size_t)(Bq / nch) * 1536 * 2 > ws_size && nch < 128) nch <<= 1;
    const int rch = Bq / nch;

    const unsigned short* xs[3] = { ACTB, ACTA, ACTB };
    unsigned short* gdst[3]     = { ACTA, ACTB, ACTA };

    for (int g = 0; g < 3; ++g) {
        for (int ch = 0; ch < nch; ++ch) {
            long r0 = (long)ch * rch;
            gemm_bt<1><<<dim3(rch / BM, 1536 / BN), dim3(256), 0, stream>>>(
                xs[g] + r0 * Cc, HB[g] + r0 * Cc, WG[g], BG[g], GATES, Cc, 768, 1536);
            gru_elem<<<dim3((rch * 32) / 256), dim3(256), 0, stream>>>(
                GATES, HF[g], out_f + GOFF[g], gdst[g], (int)r0, rch);
        }
    }

    // 5) output head: g3(bf16, ACTA) @ Wout^T -> tanh -> d_out[:, :40]
    gemm_bt<2><<<dim3(Bq / BM, 1), dim3(256), 0, stream>>>(
        ACTA, ACTA, WOUT, BOUT, out_f + GO_OUT, Cc, 1 << 30, Ss);

    (void)in_sizes; (void)n_in; (void)out_size;
}

// Round 2
// 184.501 us; speedup vs baseline: 1.0904x; 1.0904x over previous
//
#include <hip/hip_runtime.h>
#include <hip/hip_bf16.h>

// ---------------- problem constants ----------------
constexpr int Bq = 16384;   // batch
constexpr int Cc = 256;     // hidden
constexpr int Ss = 40;      // prev/out width
constexpr int KD1 = 320;    // 296 padded to 320 (5 x 64)

// ---------------- ws layout (bytes) ----------------
constexpr size_t O_WD1  = 0;          // bf16 [256][320]  163840
constexpr size_t O_WD2  = 0x30000;    // bf16 [256][256]  131072
constexpr size_t O_WG1  = 0x50000;    // bf16 [1536][256] 786432
constexpr size_t O_WG2  = 0x110000;
constexpr size_t O_WG3  = 0x1D0000;
constexpr size_t O_WOUT = 0x290000;   // bf16 [128][256]  65536
constexpr size_t O_BD1  = 0x2A0000;   // f32 [256]
constexpr size_t O_BD2  = 0x2A0400;
constexpr size_t O_BG1  = 0x2A0800;   // f32 [1536]
constexpr size_t O_BG2  = 0x2A2000;
constexpr size_t O_BG3  = 0x2A3800;
constexpr size_t O_BOUT = 0x2A5000;   // f32 [128]
constexpr size_t O_ACTA = 0x2B0000;   // bf16 [B][256]  8 MB
constexpr size_t O_ACTB = 0xAB0000;   // bf16 [B][256]
constexpr size_t O_H1   = 0x12B0000;  // bf16 [B][256]
constexpr size_t O_H2   = 0x1AB0000;
constexpr size_t O_H3   = 0x22B0000;
constexpr size_t O_XD1  = 0x2AB0000;  // bf16 [B][320] 10.5 MB  (union with GATES)
constexpr size_t O_GATES= 0x2AB0000;  // bf16 [rch][1536] up to 50.3 MB

// d_out element offsets (fp32): out[B,40], g1[B,256], g2, g3
constexpr size_t GO_OUT = 0;
constexpr size_t GO_G1  = (size_t)Bq * Ss;              // 655360
constexpr size_t GO_G2  = GO_G1 + (size_t)Bq * Cc;      // 4849664
constexpr size_t GO_G3  = GO_G2 + (size_t)Bq * Cc;      // 9043968

typedef __attribute__((ext_vector_type(8))) short bf16x8;
typedef __attribute__((ext_vector_type(4))) float f32x4;

__device__ __forceinline__ float bf2f(unsigned short h) {
    union { unsigned u; float f; } v; v.u = ((unsigned)h) << 16; return v.f;
}
__device__ __forceinline__ unsigned short f2bf(float f) {
    union { float f; unsigned u; } v; v.f = f;
    unsigned u = v.u;
    return (unsigned short)((u + 0x7FFFu + ((u >> 16) & 1u)) >> 16);
}
__device__ __forceinline__ float sigf(float x) { return 1.f / (1.f + __expf(-x)); }

// convert 8 contiguous f32 -> bf16x8 (two float4 loads)
__device__ __forceinline__ bf16x8 cvt8(const float* __restrict__ s) {
    float4 a = *(const float4*)s;
    float4 b = *(const float4*)(s + 4);
    bf16x8 o;
    o[0] = (short)f2bf(a.x); o[1] = (short)f2bf(a.y);
    o[2] = (short)f2bf(a.z); o[3] = (short)f2bf(a.w);
    o[4] = (short)f2bf(b.x); o[5] = (short)f2bf(b.y);
    o[6] = (short)f2bf(b.z); o[7] = (short)f2bf(b.w);
    return o;
}

// ---------------- prep: vectorized pack (unit = 8 output elements) ----------------
constexpr long NW1 = 256L * 320;        // Wd1 padded
constexpr long NW2 = 256L * 256;        // Wd2
constexpr long NWG = 1536L * 256;       // per-GRU gate weights (x3)
constexpr long NWO = 128L * 256;        // Wout padded rows
constexpr long NB  = 256 + 256 + 1536L * 3 + 128;   // 5248
constexpr long NX  = (long)Bq * KD1;    // Xd1
constexpr long NH  = (long)Bq * Cc;     // per h (x3)

constexpr long U_W1 = NW1 / 8;          // 10240
constexpr long U_W2 = NW2 / 8;          // 8192
constexpr long U_WG = 3 * NWG / 8;      // 147456
constexpr long U_WO = NWO / 8;          // 4096
constexpr long U_B  = (NB + 7) / 8;     // 656
constexpr long U_X  = NX / 8;           // 655360
constexpr long U_H  = 3 * NH / 8;       // 1572864
constexpr long U_TOT = U_W1 + U_W2 + U_WG + U_WO + U_B + U_X + U_H;

__global__ void prep_vec(
    const float* __restrict__ cond, const float* __restrict__ prev,
    const float* __restrict__ h1, const float* __restrict__ h2, const float* __restrict__ h3,
    const float* __restrict__ w_d1, const float* __restrict__ b_d1,
    const float* __restrict__ w_d2, const float* __restrict__ b_d2,
    const float* __restrict__ w_ih1, const float* __restrict__ w_hh1,
    const float* __restrict__ b_ih1, const float* __restrict__ b_hh1,
    const float* __restrict__ w_ih2, const float* __restrict__ w_hh2,
    const float* __restrict__ b_ih2, const float* __restrict__ b_hh2,
    const float* __restrict__ w_ih3, const float* __restrict__ w_hh3,
    const float* __restrict__ b_ih3, const float* __restrict__ b_hh3,
    const float* __restrict__ w_out, const float* __restrict__ b_out,
    char* __restrict__ ws)
{
    const long stride = (long)gridDim.x * blockDim.x;
    for (long u0 = (long)blockIdx.x * blockDim.x + threadIdx.x; u0 < U_TOT; u0 += stride) {
        long v = u0;
        if (v < U_W1) {  // Wd1 [256][320] <- [256][296] + pad
            long e = v * 8;
            int k = (int)(e % KD1), n = (int)(e / KD1);
            bf16x8 o = {0,0,0,0,0,0,0,0};
            if (k < 296) o = cvt8(w_d1 + (long)n * 296 + k);
            *(bf16x8*)((unsigned short*)(ws + O_WD1) + e) = o;
            continue;
        }
        v -= U_W1;
        if (v < U_W2) {
            long e = v * 8;
            *(bf16x8*)((unsigned short*)(ws + O_WD2) + e) = cvt8(w_d2 + e);
            continue;
        }
        v -= U_W2;
        if (v < U_WG) {  // [w_ih; w_hh] -> [1536][256] per GRU
            long vg = v;
            int g = (int)(vg / (NWG / 8)); long r8 = vg % (NWG / 8);
            long e = r8 * 8;
            int n = (int)(e / 256), k = (int)(e % 256);
            const float* wih = (g == 0) ? w_ih1 : (g == 1) ? w_ih2 : w_ih3;
            const float* whh = (g == 0) ? w_hh1 : (g == 1) ? w_hh2 : w_hh3;
            size_t off = (g == 0) ? O_WG1 : (g == 1) ? O_WG2 : O_WG3;
            const float* src = (n < 768) ? (wih + (long)n * 256 + k)
                                         : (whh + (long)(n - 768) * 256 + k);
            *(bf16x8*)((unsigned short*)(ws + off) + e) = cvt8(src);
            continue;
        }
        v -= U_WG;
        if (v < U_WO) {  // Wout [128][256], rows >= 40 zero
            long e = v * 8;
            int n = (int)(e / 256);
            bf16x8 o = {0,0,0,0,0,0,0,0};
            if (n < Ss) o = cvt8(w_out + e);
            *(bf16x8*)((unsigned short*)(ws + O_WOUT) + e) = o;
            continue;
        }
        v -= U_WO;
        if (v < U_B) {  // biases fp32, scalar (tiny)
            long ebase = v * 8;
#pragma unroll
            for (int t = 0; t < 8; ++t) {
                long j = ebase + t;
                if (j >= NB) break;
                if (j < 256) { ((float*)(ws + O_BD1))[j] = b_d1[j]; continue; }
                long j2 = j - 256;
                if (j2 < 256) { ((float*)(ws + O_BD2))[j2] = b_d2[j2]; continue; }
                j2 -= 256;
                if (j2 < 1536) { ((float*)(ws + O_BG1))[j2] = (j2 < 768) ? b_ih1[j2] : b_hh1[j2 - 768]; continue; }
                j2 -= 1536;
                if (j2 < 1536) { ((float*)(ws + O_BG2))[j2] = (j2 < 768) ? b_ih2[j2] : b_hh2[j2 - 768]; continue; }
                j2 -= 1536;
                if (j2 < 1536) { ((float*)(ws + O_BG3))[j2] = (j2 < 768) ? b_ih3[j2] : b_hh3[j2 - 768]; continue; }
                j2 -= 1536;
                ((float*)(ws + O_BOUT))[j2] = (j2 < Ss) ? b_out[j2] : 0.f;
            }
            continue;
        }
        v -= U_B;
        if (v < U_X) {  // Xd1 [B][320] = [cond(256) | prev(40) | pad(24)]
            long e = v * 8;
            int k = (int)(e % KD1); long b = e / KD1;
            bf16x8 o = {0,0,0,0,0,0,0,0};
            if (k < 256)      o = cvt8(cond + b * 256 + k);
            else if (k < 296) o = cvt8(prev + b * Ss + (k - 256));
            *(bf16x8*)((unsigned short*)(ws + O_XD1) + e) = o;
            continue;
        }
        v -= U_X;
        {   // h1..h3 -> bf16
            int g = (int)(v / (NH / 8)); long r8 = v % (NH / 8);
            long e = r8 * 8;
            const float* hp = (g == 0) ? h1 : (g == 1) ? h2 : h3;
            size_t off = (g == 0) ? O_H1 : (g == 1) ? O_H2 : O_H3;
            *(bf16x8*)((unsigned short*)(ws + off) + e) = cvt8(hp + e);
        }
    }
}

// ---------------- GEMM: C[r,n] = sum_k A[r,k] * W[n,k] + bias[n] ----------------
// m97 structure: 128x128 tile, BK=64, 4 waves (2x2), 16x16x32 bf16 MFMA,
// global_load_lds width 16, single LDS buffer, 2 barriers per K-step.
// EPI: 0 = tanh -> bf16 (ldo), 1 = raw -> bf16 (ldo), 2 = tanh -> f32, cols < Ss only
constexpr int BM = 128, BN = 128, BK = 64;

template<int EPI>
__launch_bounds__(256, 2)
__global__ void gemm_bt(const unsigned short* __restrict__ A,
                        const unsigned short* __restrict__ Ah,
                        const unsigned short* __restrict__ W,
                        const float* __restrict__ bias,
                        void* __restrict__ outp,
                        int Ka, int nsplit, int ldo)
{
    __shared__ __align__(16) unsigned short sA[BM * BK];
    __shared__ __align__(16) unsigned short sB[BN * BK];

    const int tid  = threadIdx.x;
    const int lane = tid & 63;
    const int wid  = tid >> 6;
    const int wm   = wid >> 1, wn = wid & 1;
    const long brow = (long)blockIdx.x * BM;
    const long bcol = (long)blockIdx.y * BN;
    const unsigned short* Ause = (bcol < nsplit) ? A : Ah;

    f32x4 acc[4][4];
#pragma unroll
    for (int i = 0; i < 4; i++)
#pragma unroll
        for (int j = 0; j < 4; j++) acc[i][j] = (f32x4){0.f, 0.f, 0.f, 0.f};

    const int nkt = Ka / BK;
    for (int kt = 0; kt < nkt; ++kt) {
        const long k0 = (long)kt * BK;
#pragma unroll
        for (int i = 0; i < 4; i++) {
            const int cb = i * 256 + wid * 64;     // wave-uniform chunk base
            const int c  = cb + lane;              // per-lane chunk
            const int row = c >> 3, seg = c & 7;   // 8 chunks (16B) per 64-elem row
            const unsigned short* ga = Ause + (brow + row) * Ka + k0 + seg * 8;
            const unsigned short* gw = W    + (bcol + row) * Ka + k0 + seg * 8;
            __builtin_amdgcn_global_load_lds(
                (const __attribute__((address_space(1))) void*)ga,
                (__attribute__((address_space(3))) void*)(sA + (size_t)cb * 8), 16, 0, 0);
            __builtin_amdgcn_global_load_lds(
                (const __attribute__((address_space(1))) void*)gw,
                (__attribute__((address_space(3))) void*)(sB + (size_t)cb * 8), 16, 0, 0);
        }
        __syncthreads();   // compiler emits vmcnt(0) drain before barrier

#pragma unroll
        for (int kk = 0; kk < 2; ++kk) {
            bf16x8 af[4], bfr[4];
#pragma unroll
            for (int mf = 0; mf < 4; ++mf)
                af[mf] = *(const bf16x8*)&sA[(wm * 64 + mf * 16 + (lane & 15)) * BK + kk * 32 + (lane >> 4) * 8];
#pragma unroll
            for (int nf = 0; nf < 4; ++nf)
                bfr[nf] = *(const bf16x8*)&sB[(wn * 64 + nf * 16 + (lane & 15)) * BK + kk * 32 + (lane >> 4) * 8];
#pragma unroll
            for (int mf = 0; mf < 4; ++mf)
#pragma unroll
                for (int nf = 0; nf < 4; ++nf)
                    acc[mf][nf] = __builtin_amdgcn_mfma_f32_16x16x32_bf16(af[mf], bfr[nf], acc[mf][nf], 0, 0, 0);
        }
        __syncthreads();
    }

    // epilogue: C/D layout col = lane&15, row = (lane>>4)*4 + j
    const int lr4 = (lane >> 4) * 4;
    const int lc  = lane & 15;
#pragma unroll
    for (int mf = 0; mf < 4; ++mf) {
#pragma unroll
        for (int nf = 0; nf < 4; ++nf) {
            const long n = bcol + wn * 64 + nf * 16 + lc;
            const float bs = bias[n];
            f32x4 v = acc[mf][nf];
#pragma unroll
            for (int j = 0; j < 4; ++j) {
                const long r = brow + wm * 64 + mf * 16 + lr4 + j;
                float val = v[j] + bs;
                if constexpr (EPI == 0) {
                    ((unsigned short*)outp)[r * ldo + n] = f2bf(tanhf(val));
                } else if constexpr (EPI == 1) {
                    ((unsigned short*)outp)[r * ldo + n] = f2bf(val);
                } else {
                    if (n < Ss) ((float*)outp)[r * Ss + n] = tanhf(val);
                }
            }
        }
    }
}

// ---------------- GRU elementwise ----------------
// gates: bf16 [rch][1536] local rows: [i_r i_z i_n | h_r h_z h_n] each 256 wide
__global__ void gru_elem(const unsigned short* __restrict__ gates,
                         const float* __restrict__ h,
                         float* __restrict__ gout,        // d_out + region, global rows
                         unsigned short* __restrict__ actout, // bf16 [B][256], global rows
                         int r0, int rch)
{
    int u = blockIdx.x * blockDim.x + threadIdx.x;
    if (u >= rch * 32) return;
    const int lr = u >> 5;
    const int c8 = (u & 31) << 3;
    const long b = (long)r0 + lr;

    const unsigned short* grow = gates + (size_t)lr * 1536 + c8;
    bf16x8 ir  = *(const bf16x8*)(grow);
    bf16x8 iz  = *(const bf16x8*)(grow + 256);
    bf16x8 inn = *(const bf16x8*)(grow + 512);
    bf16x8 hr  = *(const bf16x8*)(grow + 768);
    bf16x8 hz  = *(const bf16x8*)(grow + 1024);
    bf16x8 hn  = *(const bf16x8*)(grow + 1280);

    float hvf[8];
    *(float4*)&hvf[0] = *(const float4*)(h + b * 256 + c8);
    *(float4*)&hvf[4] = *(const float4*)(h + b * 256 + c8 + 4);

    float gf[8];
    unsigned short gb[8];
#pragma unroll
    for (int j = 0; j < 8; ++j) {
        float r = sigf(bf2f((unsigned short)ir[j]) + bf2f((unsigned short)hr[j]));
        float z = sigf(bf2f((unsigned short)iz[j]) + bf2f((unsigned short)hz[j]));
        float n = tanhf(bf2f((unsigned short)inn[j]) + r * bf2f((unsigned short)hn[j]));
        float g = (1.f - z) * n + z * hvf[j];
        gf[j] = g; gb[j] = f2bf(g);
    }
    *(float4*)(gout + b * 256 + c8)     = make_float4(gf[0], gf[1], gf[2], gf[3]);
    *(float4*)(gout + b * 256 + c8 + 4) = make_float4(gf[4], gf[5], gf[6], gf[7]);
    bf16x8 ov;
#pragma unroll
    for (int j = 0; j < 8; ++j) ov[j] = (short)gb[j];
    *(bf16x8*)(actout + b * 256 + c8) = ov;
}

// ---------------- host launch ----------------
extern "C" void kernel_launch(void* const* d_in, const int* in_sizes, int n_in,
                              void* d_out, int out_size, void* d_ws, size_t ws_size,
                              hipStream_t stream)
{
    const float* cond  = (const float*)d_in[0];
    const float* prev  = (const float*)d_in[1];
    const float* h1    = (const float*)d_in[2];
    const float* h2    = (const float*)d_in[3];
    const float* h3    = (const float*)d_in[4];
    const float* w_d1  = (const float*)d_in[5];
    const float* b_d1  = (const float*)d_in[6];
    const float* w_d2  = (const float*)d_in[7];
    const float* b_d2  = (const float*)d_in[8];
    const float* w_ih1 = (const float*)d_in[9];
    const float* w_hh1 = (const float*)d_in[10];
    const float* b_ih1 = (const float*)d_in[11];
    const float* b_hh1 = (const float*)d_in[12];
    const float* w_ih2 = (const float*)d_in[13];
    const float* w_hh2 = (const float*)d_in[14];
    const float* b_ih2 = (const float*)d_in[15];
    const float* b_hh2 = (const float*)d_in[16];
    const float* w_ih3 = (const float*)d_in[17];
    const float* w_hh3 = (const float*)d_in[18];
    const float* b_ih3 = (const float*)d_in[19];
    const float* b_hh3 = (const float*)d_in[20];
    const float* w_out = (const float*)d_in[21];
    const float* b_out = (const float*)d_in[22];

    char* ws = (char*)d_ws;
    float* out_f = (float*)d_out;

    const unsigned short* WD1  = (const unsigned short*)(ws + O_WD1);
    const unsigned short* WD2  = (const unsigned short*)(ws + O_WD2);
    const unsigned short* WOUT = (const unsigned short*)(ws + O_WOUT);
    const float* BD1  = (const float*)(ws + O_BD1);
    const float* BD2  = (const float*)(ws + O_BD2);
    const float* BOUT = (const float*)(ws + O_BOUT);
    const unsigned short* XD1 = (const unsigned short*)(ws + O_XD1);
    unsigned short* ACTA = (unsigned short*)(ws + O_ACTA);
    unsigned short* ACTB = (unsigned short*)(ws + O_ACTB);
    unsigned short* GATES = (unsigned short*)(ws + O_GATES);

    const unsigned short* WG[3] = {
        (const unsigned short*)(ws + O_WG1),
        (const unsigned short*)(ws + O_WG2),
        (const unsigned short*)(ws + O_WG3) };
    const float* BG[3] = {
        (const float*)(ws + O_BG1), (const float*)(ws + O_BG2), (const float*)(ws + O_BG3) };
    const unsigned short* HB[3] = {
        (const unsigned short*)(ws + O_H1),
        (const unsigned short*)(ws + O_H2),
        (const unsigned short*)(ws + O_H3) };
    const float* HF[3] = { h1, h2, h3 };
    const size_t GOFF[3] = { GO_G1, GO_G2, GO_G3 };

    // 1) prep (vectorized, grid-stride)
    prep_vec<<<dim3(2048), dim3(256), 0, stream>>>(
        cond, prev, h1, h2, h3, w_d1, b_d1, w_d2, b_d2,
        w_ih1, w_hh1, b_ih1, b_hh1, w_ih2, w_hh2, b_ih2, b_hh2,
        w_ih3, w_hh3, b_ih3, b_hh3, w_out, b_out, ws);

    // 2) dense1: Xd1[B,320] -> tanh -> ACTA bf16 [B,256]
    gemm_bt<0><<<dim3(Bq / BM, Cc / BN), dim3(256), 0, stream>>>(
        XD1, XD1, WD1, BD1, ACTA, KD1, 1 << 30, Cc);
    // 3) dense2: ACTA -> tanh -> ACTB
    gemm_bt<0><<<dim3(Bq / BM, Cc / BN), dim3(256), 0, stream>>>(
        ACTA, ACTA, WD2, BD2, ACTB, Cc, 1 << 30, Cc);

    // 4) GRUs (gates GEMM + elementwise), chunked over B if ws is small
    int nch = 1;
    while (O_GATES + (size_t)(Bq / nch) * 1536 * 2 > ws_size && nch < 128) nch <<= 1;
    const int rch = Bq / nch;

    const unsigned short* xs[3] = { ACTB, ACTA, ACTB };
    unsigned short* gdst[3]     = { ACTA, ACTB, ACTA };

    for (int g = 0; g < 3; ++g) {
        for (int ch = 0; ch < nch; ++ch) {
            long r0 = (long)ch * rch;
            gemm_bt<1><<<dim3(rch / BM, 1536 / BN), dim3(256), 0, stream>>>(
                xs[g] + r0 * Cc, HB[g] + r0 * Cc, WG[g], BG[g], GATES, Cc, 768, 1536);
            gru_elem<<<dim3((rch * 32) / 256), dim3(256), 0, stream>>>(
                GATES, HF[g], out_f + GOFF[g], gdst[g], (int)r0, rch);
        }
    }

    // 5) output head: g3(bf16, ACTA) @ Wout^T -> tanh -> d_out[:, :40]
    gemm_bt<2><<<dim3(Bq / BM, 1), dim3(256), 0, stream>>>(
        ACTA, ACTA, WOUT, BOUT, out_f + GO_OUT, Cc, 1 << 30, Ss);

    (void)in_sizes; (void)n_in; (void)out_size;
}

// Round 3
// 149.298 us; speedup vs baseline: 1.3475x; 1.2358x over previous
//
#include <hip/hip_runtime.h>
#include <hip/hip_bf16.h>

// ---------------- problem constants ----------------
constexpr int Bq = 16384;   // batch
constexpr int Cc = 256;     // hidden
constexpr int Ss = 40;      // prev/out width
constexpr int KD1 = 320;    // 296 padded to 320 (5 x 64)

// ---------------- ws layout (bytes); ws_size = 256 MiB (fill evidence R2) ----
constexpr size_t O_WD1  = 0;          // bf16 [256][320]  160KB
constexpr size_t O_WD2  = 0x30000;    // bf16 [256][256]  128KB
constexpr size_t O_WOUT = 0x50000;    // bf16 [128][256]  64KB
constexpr size_t O_WGF1 = 0x60000;    // bf16 [768][512]  768KB  ([W_ih | W_hh])
constexpr size_t O_WGF2 = 0x120000;
constexpr size_t O_WGF3 = 0x1E0000;
constexpr size_t O_BD1  = 0x2A0000;   // f32 [256]
constexpr size_t O_BD2  = 0x2A0400;   // f32 [256]
constexpr size_t O_BOUT = 0x2A0800;   // f32 [128] (pad 0)
constexpr size_t O_BG1  = 0x2A1000;   // f32 [1024]: [0..511]=b_ih+b_hh, [512..767]=b_ih_n, [768..1023]=b_hh_n
constexpr size_t O_BG2  = 0x2A2000;
constexpr size_t O_BG3  = 0x2A3000;
constexpr size_t O_XD1  = 0x2B0000;   // bf16 [B][320]  10.5MB
constexpr size_t O_T1   = 0xCB0000;   // bf16 [B][256]  8MB   (dense1 out)
constexpr size_t O_A1   = 0x14B0000;  // bf16 [B][512]  16MB  (left=dense2 out, right=h1)
constexpr size_t O_A2   = 0x24B0000;  // bf16 [B][512]        (left=g1, right=h2)
constexpr size_t O_A3   = 0x34B0000;  // bf16 [B][512]        (left=g2, right=h3)
constexpr size_t O_ACT3 = 0x44B0000;  // bf16 [B][256]  8MB   (g3, head input)

// d_out element offsets (fp32): out[B,40], g1[B,256], g2, g3
constexpr size_t GO_OUT = 0;
constexpr size_t GO_G1  = (size_t)Bq * Ss;
constexpr size_t GO_G2  = GO_G1 + (size_t)Bq * Cc;
constexpr size_t GO_G3  = GO_G2 + (size_t)Bq * Cc;

typedef __attribute__((ext_vector_type(8))) short bf16x8;
typedef __attribute__((ext_vector_type(4))) float f32x4;

__device__ __forceinline__ float bf2f(unsigned short h) {
    union { unsigned u; float f; } v; v.u = ((unsigned)h) << 16; return v.f;
}
__device__ __forceinline__ unsigned short f2bf(float f) {
    union { float f; unsigned u; } v; v.f = f;
    unsigned u = v.u;
    return (unsigned short)((u + 0x7FFFu + ((u >> 16) & 1u)) >> 16);
}
__device__ __forceinline__ float sigf(float x) { return 1.f / (1.f + __expf(-x)); }

__device__ __forceinline__ bf16x8 cvt8(const float* __restrict__ s) {
    float4 a = *(const float4*)s;
    float4 b = *(const float4*)(s + 4);
    bf16x8 o;
    o[0] = (short)f2bf(a.x); o[1] = (short)f2bf(a.y);
    o[2] = (short)f2bf(a.z); o[3] = (short)f2bf(a.w);
    o[4] = (short)f2bf(b.x); o[5] = (short)f2bf(b.y);
    o[6] = (short)f2bf(b.z); o[7] = (short)f2bf(b.w);
    return o;
}

// ---------------- prep: vectorized pack (unit = 8 output elements) ----------------
constexpr long NW1  = 256L * 320;
constexpr long NW2  = 256L * 256;
constexpr long NWGF = 768L * 512;            // per GRU
constexpr long NWO  = 128L * 256;
constexpr long NBIA = 256 + 256 + 128 + 3L * 1024;  // 3712
constexpr long NX   = (long)Bq * KD1;
constexpr long NH   = (long)Bq * Cc;         // per h

constexpr long U_W1 = NW1 / 8;
constexpr long U_W2 = NW2 / 8;
constexpr long U_WG = 3 * NWGF / 8;
constexpr long U_WO = NWO / 8;
constexpr long U_B  = (NBIA + 7) / 8;        // 464
constexpr long U_X  = NX / 8;
constexpr long U_H  = 3 * NH / 8;
constexpr long U_TOT = U_W1 + U_W2 + U_WG + U_WO + U_B + U_X + U_H;

__global__ void prep_vec(
    const float* __restrict__ cond, const float* __restrict__ prev,
    const float* __restrict__ h1, const float* __restrict__ h2, const float* __restrict__ h3,
    const float* __restrict__ w_d1, const float* __restrict__ b_d1,
    const float* __restrict__ w_d2, const float* __restrict__ b_d2,
    const float* __restrict__ w_ih1, const float* __restrict__ w_hh1,
    const float* __restrict__ b_ih1, const float* __restrict__ b_hh1,
    const float* __restrict__ w_ih2, const float* __restrict__ w_hh2,
    const float* __restrict__ b_ih2, const float* __restrict__ b_hh2,
    const float* __restrict__ w_ih3, const float* __restrict__ w_hh3,
    const float* __restrict__ b_ih3, const float* __restrict__ b_hh3,
    const float* __restrict__ w_out, const float* __restrict__ b_out,
    char* __restrict__ ws)
{
    const long stride = (long)gridDim.x * blockDim.x;
    for (long u0 = (long)blockIdx.x * blockDim.x + threadIdx.x; u0 < U_TOT; u0 += stride) {
        long v = u0;
        if (v < U_W1) {  // Wd1 [256][320] <- [256][296] + pad
            long e = v * 8;
            int k = (int)(e % KD1), n = (int)(e / KD1);
            bf16x8 o = {0,0,0,0,0,0,0,0};
            if (k < 296) o = cvt8(w_d1 + (long)n * 296 + k);
            *(bf16x8*)((unsigned short*)(ws + O_WD1) + e) = o;
            continue;
        }
        v -= U_W1;
        if (v < U_W2) {
            long e = v * 8;
            *(bf16x8*)((unsigned short*)(ws + O_WD2) + e) = cvt8(w_d2 + e);
            continue;
        }
        v -= U_W2;
        if (v < U_WG) {  // WGF_g [768][512] = [W_ih | W_hh] column-concat
            int g = (int)(v / (NWGF / 8)); long r8 = v % (NWGF / 8);
            long e = r8 * 8;
            int n = (int)(e >> 9), k = (int)(e & 511);
            const float* wih = (g == 0) ? w_ih1 : (g == 1) ? w_ih2 : w_ih3;
            const float* whh = (g == 0) ? w_hh1 : (g == 1) ? w_hh2 : w_hh3;
            size_t off = (g == 0) ? O_WGF1 : (g == 1) ? O_WGF2 : O_WGF3;
            const float* src = (k < 256) ? (wih + (long)n * 256 + k)
                                         : (whh + (long)n * 256 + (k - 256));
            *(bf16x8*)((unsigned short*)(ws + off) + e) = cvt8(src);
            continue;
        }
        v -= U_WG;
        if (v < U_WO) {  // Wout [128][256], rows >= 40 zero
            long e = v * 8;
            int n = (int)(e / 256);
            bf16x8 o = {0,0,0,0,0,0,0,0};
            if (n < Ss) o = cvt8(w_out + e);
            *(bf16x8*)((unsigned short*)(ws + O_WOUT) + e) = o;
            continue;
        }
        v -= U_WO;
        if (v < U_B) {  // biases fp32, scalar (tiny)
            long ebase = v * 8;
#pragma unroll
            for (int t = 0; t < 8; ++t) {
                long j = ebase + t;
                if (j >= NBIA) break;
                if (j < 256) { ((float*)(ws + O_BD1))[j] = b_d1[j]; continue; }
                long j2 = j - 256;
                if (j2 < 256) { ((float*)(ws + O_BD2))[j2] = b_d2[j2]; continue; }
                j2 -= 256;
                if (j2 < 128) { ((float*)(ws + O_BOUT))[j2] = (j2 < Ss) ? b_out[j2] : 0.f; continue; }
                j2 -= 128;
                int g = (int)(j2 / 1024); int jj = (int)(j2 % 1024);
                const float* bih = (g == 0) ? b_ih1 : (g == 1) ? b_ih2 : b_ih3;
                const float* bhh = (g == 0) ? b_hh1 : (g == 1) ? b_hh2 : b_hh3;
                float* dst = (float*)(ws + ((g == 0) ? O_BG1 : (g == 1) ? O_BG2 : O_BG3));
                float val;
                if (jj < 512)      val = bih[jj] + bhh[jj];
                else if (jj < 768) val = bih[jj];           // b_ih_n[jj-512]
                else               val = bhh[jj - 256];     // b_hh_n[jj-768]
                dst[jj] = val;
            }
            continue;
        }
        v -= U_B;
        if (v < U_X) {  // Xd1 [B][320] = [cond(256) | prev(40) | pad(24)]
            long e = v * 8;
            int k = (int)(e % KD1); long b = e / KD1;
            bf16x8 o = {0,0,0,0,0,0,0,0};
            if (k < 256)      o = cvt8(cond + b * 256 + k);
            else if (k < 296) o = cvt8(prev + b * Ss + (k - 256));
            *(bf16x8*)((unsigned short*)(ws + O_XD1) + e) = o;
            continue;
        }
        v -= U_X;
        {   // h1..h3 -> bf16 into A1/A2/A3 right halves (stride 512, col+256)
            int g = (int)(v / (NH / 8)); long r8 = v % (NH / 8);
            long e = r8 * 8;
            long row = e >> 8; int k = (int)(e & 255);
            const float* hp = (g == 0) ? h1 : (g == 1) ? h2 : h3;
            size_t off = (g == 0) ? O_A1 : (g == 1) ? O_A2 : O_A3;
            *(bf16x8*)((unsigned short*)(ws + off) + row * 512 + 256 + k) = cvt8(hp + e);
        }
    }
}

// ---------------- GEMM: C[r,n] = sum_k A[r,k] * W[n,k] + bias[n] ----------------
// EPI: 0 = tanh -> bf16 (ldo), 2 = tanh -> f32, cols < Ss only
constexpr int BM = 128, BN = 128, BK = 64;

template<int EPI>
__launch_bounds__(256, 2)
__global__ void gemm_bt(const unsigned short* __restrict__ A,
                        const unsigned short* __restrict__ W,
                        const float* __restrict__ bias,
                        void* __restrict__ outp,
                        int Ka, int ldo)
{
    __shared__ __align__(16) unsigned short sA[BM * BK];
    __shared__ __align__(16) unsigned short sB[BN * BK];

    const int tid  = threadIdx.x;
    const int lane = tid & 63;
    const int wid  = tid >> 6;
    const int wm   = wid >> 1, wn = wid & 1;
    const long brow = (long)blockIdx.x * BM;
    const long bcol = (long)blockIdx.y * BN;

    f32x4 acc[4][4];
#pragma unroll
    for (int i = 0; i < 4; i++)
#pragma unroll
        for (int j = 0; j < 4; j++) acc[i][j] = (f32x4){0.f, 0.f, 0.f, 0.f};

    const int nkt = Ka / BK;
    for (int kt = 0; kt < nkt; ++kt) {
        const long k0 = (long)kt * BK;
#pragma unroll
        for (int i = 0; i < 4; i++) {
            const int cb = i * 256 + wid * 64;
            const int c  = cb + lane;
            const int row = c >> 3, seg = c & 7;
            const unsigned short* ga = A + (brow + row) * Ka + k0 + seg * 8;
            const unsigned short* gw = W + (bcol + row) * Ka + k0 + seg * 8;
            __builtin_amdgcn_global_load_lds(
                (const __attribute__((address_space(1))) void*)ga,
                (__attribute__((address_space(3))) void*)(sA + (size_t)cb * 8), 16, 0, 0);
            __builtin_amdgcn_global_load_lds(
                (const __attribute__((address_space(1))) void*)gw,
                (__attribute__((address_space(3))) void*)(sB + (size_t)cb * 8), 16, 0, 0);
        }
        __syncthreads();

#pragma unroll
        for (int kk = 0; kk < 2; ++kk) {
            bf16x8 af[4], bfr[4];
#pragma unroll
            for (int mf = 0; mf < 4; ++mf)
                af[mf] = *(const bf16x8*)&sA[(wm * 64 + mf * 16 + (lane & 15)) * BK + kk * 32 + (lane >> 4) * 8];
#pragma unroll
            for (int nf = 0; nf < 4; ++nf)
                bfr[nf] = *(const bf16x8*)&sB[(wn * 64 + nf * 16 + (lane & 15)) * BK + kk * 32 + (lane >> 4) * 8];
#pragma unroll
            for (int mf = 0; mf < 4; ++mf)
#pragma unroll
                for (int nf = 0; nf < 4; ++nf)
                    acc[mf][nf] = __builtin_amdgcn_mfma_f32_16x16x32_bf16(af[mf], bfr[nf], acc[mf][nf], 0, 0, 0);
        }
        __syncthreads();
    }

    const int lr4 = (lane >> 4) * 4;
    const int lc  = lane & 15;
#pragma unroll
    for (int mf = 0; mf < 4; ++mf) {
#pragma unroll
        for (int nf = 0; nf < 4; ++nf) {
            const long n = bcol + wn * 64 + nf * 16 + lc;
            const float bs = bias[n];
            f32x4 v = acc[mf][nf];
#pragma unroll
            for (int j = 0; j < 4; ++j) {
                const long r = brow + wm * 64 + mf * 16 + lr4 + j;
                float val = v[j] + bs;
                if constexpr (EPI == 0) {
                    ((unsigned short*)outp)[r * ldo + n] = f2bf(tanhf(val));
                } else {
                    if (n < Ss) ((float*)outp)[r * Ss + n] = tanhf(val);
                }
            }
        }
    }
}

// ---------------- fused GRU ----------------
// A = [x | h] bf16 [B][512];  WGF = [W_ih | W_hh] bf16 [768][512]
// (rows 0..255 = r-gate, 256..511 = z-gate, 512..767 = n-gate)
// BG f32 [1024]: [0..511] = b_ih+b_hh (r,z), [512..767] = b_ih_n, [768..1023] = b_hh_n
// Block: 128 rows x 32 output cols; 4 waves stacked in M (32 rows each).
// K=512 in 8 steps of 64; r,z accumulate all 8; i_n steps 0..3 (x half),
// h_n steps 4..7 (h half). Epilogue = full GRU cell in registers.
__launch_bounds__(256, 2)
__global__ void gru_fused(const unsigned short* __restrict__ A,
                          const unsigned short* __restrict__ WGF,
                          const float* __restrict__ BG,
                          const float* __restrict__ h,
                          float* __restrict__ gout,
                          unsigned short* __restrict__ actout,
                          int act_stride)
{
    __shared__ __align__(16) unsigned short sA[128 * 64];     // 16KB
    __shared__ __align__(16) unsigned short sW[3 * 32 * 64];  // 12KB

    const int tid  = threadIdx.x;
    const int lane = tid & 63;
    const int wid  = tid >> 6;
    const long brow = (long)blockIdx.x * 128;
    const int  c0   = blockIdx.y * 32;

    f32x4 accR[2][2], accZ[2][2], accI[2][2], accH[2][2];
#pragma unroll
    for (int i = 0; i < 2; i++)
#pragma unroll
        for (int j = 0; j < 2; j++) {
            accR[i][j] = (f32x4){0.f,0.f,0.f,0.f};
            accZ[i][j] = (f32x4){0.f,0.f,0.f,0.f};
            accI[i][j] = (f32x4){0.f,0.f,0.f,0.f};
            accH[i][j] = (f32x4){0.f,0.f,0.f,0.f};
        }

    for (int kt = 0; kt < 8; ++kt) {
        const int k0 = kt * 64;
        // stage A tile [128][64]
#pragma unroll
        for (int i = 0; i < 4; i++) {
            const int cb = i * 256 + wid * 64;
            const int c  = cb + lane;
            const int row = c >> 3, seg = c & 7;
            const unsigned short* ga = A + (brow + row) * 512 + k0 + seg * 8;
            __builtin_amdgcn_global_load_lds(
                (const __attribute__((address_space(1))) void*)ga,
                (__attribute__((address_space(3))) void*)(sA + (size_t)cb * 8), 16, 0, 0);
        }
        // stage 3 W slices [32][64]: r rows c0+, z rows 256+c0+, n rows 512+c0+
#pragma unroll
        for (int s = 0; s < 3; s++) {
            const int rowbase = s * 256 + c0;
            const int r32 = tid >> 3, seg = tid & 7;
            const unsigned short* gw = WGF + (long)(rowbase + r32) * 512 + k0 + seg * 8;
            const int cb = s * 256 + wid * 64;   // wave-uniform chunk base within sW
            __builtin_amdgcn_global_load_lds(
                (const __attribute__((address_space(1))) void*)gw,
                (__attribute__((address_space(3))) void*)(sW + (size_t)cb * 8), 16, 0, 0);
        }
        __syncthreads();

#pragma unroll
        for (int kk = 0; kk < 2; ++kk) {
            bf16x8 af[2], wfr[3][2];
#pragma unroll
            for (int mf = 0; mf < 2; ++mf)
                af[mf] = *(const bf16x8*)&sA[(wid * 32 + mf * 16 + (lane & 15)) * 64 + kk * 32 + (lane >> 4) * 8];
#pragma unroll
            for (int s = 0; s < 3; ++s)
#pragma unroll
                for (int nf = 0; nf < 2; ++nf)
                    wfr[s][nf] = *(const bf16x8*)&sW[(s * 32 + nf * 16 + (lane & 15)) * 64 + kk * 32 + (lane >> 4) * 8];
            if (kt < 4) {
#pragma unroll
                for (int mf = 0; mf < 2; ++mf)
#pragma unroll
                    for (int nf = 0; nf < 2; ++nf) {
                        accR[mf][nf] = __builtin_amdgcn_mfma_f32_16x16x32_bf16(af[mf], wfr[0][nf], accR[mf][nf], 0, 0, 0);
                        accZ[mf][nf] = __builtin_amdgcn_mfma_f32_16x16x32_bf16(af[mf], wfr[1][nf], accZ[mf][nf], 0, 0, 0);
                        accI[mf][nf] = __builtin_amdgcn_mfma_f32_16x16x32_bf16(af[mf], wfr[2][nf], accI[mf][nf], 0, 0, 0);
                    }
            } else {
#pragma unroll
                for (int mf = 0; mf < 2; ++mf)
#pragma unroll
                    for (int nf = 0; nf < 2; ++nf) {
                        accR[mf][nf] = __builtin_amdgcn_mfma_f32_16x16x32_bf16(af[mf], wfr[0][nf], accR[mf][nf], 0, 0, 0);
                        accZ[mf][nf] = __builtin_amdgcn_mfma_f32_16x16x32_bf16(af[mf], wfr[1][nf], accZ[mf][nf], 0, 0, 0);
                        accH[mf][nf] = __builtin_amdgcn_mfma_f32_16x16x32_bf16(af[mf], wfr[2][nf], accH[mf][nf], 0, 0, 0);
                    }
            }
        }
        __syncthreads();
    }

    // epilogue: GRU cell math, C/D layout col=lane&15, row=(lane>>4)*4+j
    const int lr4 = (lane >> 4) * 4;
    const int lc  = lane & 15;
#pragma unroll
    for (int mf = 0; mf < 2; ++mf) {
#pragma unroll
        for (int nf = 0; nf < 2; ++nf) {
            const int col = c0 + nf * 16 + lc;
            const float br = BG[col], bz = BG[256 + col];
            const float bi = BG[512 + col], bh = BG[768 + col];
#pragma unroll
            for (int j = 0; j < 4; ++j) {
                const long r = brow + wid * 32 + mf * 16 + lr4 + j;
                const float rr = sigf(accR[mf][nf][j] + br);
                const float zz = sigf(accZ[mf][nf][j] + bz);
                const float nn = tanhf(accI[mf][nf][j] + bi + rr * (accH[mf][nf][j] + bh));
                const float hv = h[r * 256 + col];
                const float g = (1.f - zz) * nn + zz * hv;
                gout[r * 256 + col] = g;
                actout[r * (long)act_stride + col] = f2bf(g);
            }
        }
    }
}

// ---------------- host launch ----------------
extern "C" void kernel_launch(void* const* d_in, const int* in_sizes, int n_in,
                              void* d_out, int out_size, void* d_ws, size_t ws_size,
                              hipStream_t stream)
{
    const float* cond  = (const float*)d_in[0];
    const float* prev  = (const float*)d_in[1];
    const float* h1    = (const float*)d_in[2];
    const float* h2    = (const float*)d_in[3];
    const float* h3    = (const float*)d_in[4];
    const float* w_d1  = (const float*)d_in[5];
    const float* b_d1  = (const float*)d_in[6];
    const float* w_d2  = (const float*)d_in[7];
    const float* b_d2  = (const float*)d_in[8];
    const float* w_ih1 = (const float*)d_in[9];
    const float* w_hh1 = (const float*)d_in[10];
    const float* b_ih1 = (const float*)d_in[11];
    const float* b_hh1 = (const float*)d_in[12];
    const float* w_ih2 = (const float*)d_in[13];
    const float* w_hh2 = (const float*)d_in[14];
    const float* b_ih2 = (const float*)d_in[15];
    const float* b_hh2 = (const float*)d_in[16];
    const float* w_ih3 = (const float*)d_in[17];
    const float* w_hh3 = (const float*)d_in[18];
    const float* b_ih3 = (const float*)d_in[19];
    const float* b_hh3 = (const float*)d_in[20];
    const float* w_out = (const float*)d_in[21];
    const float* b_out = (const float*)d_in[22];

    char* ws = (char*)d_ws;
    float* out_f = (float*)d_out;

    // 1) prep
    prep_vec<<<dim3(2048), dim3(256), 0, stream>>>(
        cond, prev, h1, h2, h3, w_d1, b_d1, w_d2, b_d2,
        w_ih1, w_hh1, b_ih1, b_hh1, w_ih2, w_hh2, b_ih2, b_hh2,
        w_ih3, w_hh3, b_ih3, b_hh3, w_out, b_out, ws);

    // 2) dense1: Xd1[B,320] -> tanh -> T1 bf16 [B,256]
    gemm_bt<0><<<dim3(Bq / BM, Cc / BN), dim3(256), 0, stream>>>(
        (const unsigned short*)(ws + O_XD1), (const unsigned short*)(ws + O_WD1),
        (const float*)(ws + O_BD1), ws + O_T1, KD1, Cc);
    // 3) dense2: T1 -> tanh -> A1 left half (ldo=512)
    gemm_bt<0><<<dim3(Bq / BM, Cc / BN), dim3(256), 0, stream>>>(
        (const unsigned short*)(ws + O_T1), (const unsigned short*)(ws + O_WD2),
        (const float*)(ws + O_BD2), ws + O_A1, Cc, 512);

    // 4) fused GRUs
    const size_t OA[3]   = { O_A1, O_A2, O_A3 };
    const size_t OW[3]   = { O_WGF1, O_WGF2, O_WGF3 };
    const size_t OB[3]   = { O_BG1, O_BG2, O_BG3 };
    const float* HF[3]   = { h1, h2, h3 };
    const size_t GOFF[3] = { GO_G1, GO_G2, GO_G3 };
    const size_t OACT[3] = { O_A2, O_A3, O_ACT3 };   // g -> next A left half / head input
    const int    AST[3]  = { 512, 512, 256 };

    for (int g = 0; g < 3; ++g) {
        gru_fused<<<dim3(Bq / 128, Cc / 32), dim3(256), 0, stream>>>(
            (const unsigned short*)(ws + OA[g]), (const unsigned short*)(ws + OW[g]),
            (const float*)(ws + OB[g]), HF[g],
            out_f + GOFF[g], (unsigned short*)(ws + OACT[g]), AST[g]);
    }

    // 5) output head: g3 @ Wout^T -> tanh -> d_out[:, :40]
    gemm_bt<2><<<dim3(Bq / BM, 1), dim3(256), 0, stream>>>(
        (const unsigned short*)(ws + O_ACT3), (const unsigned short*)(ws + O_WOUT),
        (const float*)(ws + O_BOUT), out_f + GO_OUT, Cc, Ss);

    (void)in_sizes; (void)n_in; (void)out_size; (void)ws_size;
}